// Round 9
// baseline (481.673 us; speedup 1.0000x reference)
//
#include <hip/hip_runtime.h>
#include <hip/hip_bf16.h>

#define B_      16
#define C_      256
#define H_      56
#define W_      56
#define HW_     3136
#define G_      64
#define P_      49
#define NTOK    50176
#define HEADS_  8
#define DH_     32
#define SCALE_  0.0625f
#define EPS_    1e-5f

typedef short bf16x8 __attribute__((ext_vector_type(8)));
typedef short bf16x4_t __attribute__((ext_vector_type(4)));
typedef float f32x4  __attribute__((ext_vector_type(4)));
using bf16 = __hip_bfloat16;

__device__ __forceinline__ float b2f(short s) {
  union { float f; unsigned u; } v; v.u = ((unsigned)(unsigned short)s) << 16; return v.f;
}
__device__ __forceinline__ short f2b(float f) {   // RNE via intrinsic (packed cvt)
  __hip_bfloat16 h = __float2bfloat16(f);
  return *reinterpret_cast<short*>(&h);
}

// ---------------------------------------------------------------------------
// prep: weights -> [N][K] bf16; bias -> bt[h][key(64)][q*4+qni] bf16
// ---------------------------------------------------------------------------
__global__ __launch_bounds__(256)
void prep_kernel(const float* __restrict__ wqkv, const float* __restrict__ wmerge,
                 const float* __restrict__ w1, const float* __restrict__ w2,
                 const float* __restrict__ btab, const int* __restrict__ relidx,
                 bf16* __restrict__ wqkvT, bf16* __restrict__ wmergeT,
                 bf16* __restrict__ w1T, bf16* __restrict__ w2T,
                 short* __restrict__ bt)
{
  int idx = blockIdx.x * 256 + threadIdx.x;
  if (idx < 196608) { int n = idx >> 8, k = idx & 255;
    wqkvT[idx] = __float2bfloat16(wqkv[k * 768 + n]); return; }
  idx -= 196608;
  if (idx < 65536) { int n = idx >> 8, k = idx & 255;
    wmergeT[idx] = __float2bfloat16(wmerge[k * 256 + n]); return; }
  idx -= 65536;
  if (idx < 262144) { int n = idx >> 8, k = idx & 255;
    w1T[idx] = __float2bfloat16(w1[k * 1024 + n]); return; }
  idx -= 262144;
  if (idx < 262144) { int n = idx >> 10, k = idx & 1023;
    w2T[idx] = __float2bfloat16(w2[k * 256 + n]); return; }
  idx -= 262144;
  if (idx < 32768) {
    int h = idx >> 12, rest = idx & 4095;
    int key = rest >> 6, col = rest & 63;
    int q = col >> 2, qni = col & 3;
    int query = qni * 16 + q;
    float v = 0.f;
    if (key < P_ && query < P_) v = btab[relidx[query * P_ + key] * HEADS_ + h];
    bt[idx] = f2b(v);
  }
}

// ---------------------------------------------------------------------------
// ingest: coalesced BCHW float4 read -> LDS transpose -> LN1 -> xtok + y
// ---------------------------------------------------------------------------
__global__ __launch_bounds__(256)
void ingest_kernel(const float* __restrict__ x, const float* __restrict__ gam,
                   const float* __restrict__ bet, short* __restrict__ xtok,
                   short* __restrict__ y)
{
  __shared__ short Lt[56 * 260];
  const int h = blockIdx.x % 56, b = blockIdx.x / 56;
  const int tid = threadIdx.x;

  const float* xb = x + (size_t)b * 256 * HW_ + h * 56;
#pragma unroll
  for (int i = 0; i < 14; i++) {
    int idx = i * 256 + tid;
    int c = idx / 14, w4 = idx - c * 14;
    float4 v = *(const float4*)(xb + (size_t)c * HW_ + w4 * 4);
    Lt[(w4 * 4 + 0) * 260 + c] = f2b(v.x);
    Lt[(w4 * 4 + 1) * 260 + c] = f2b(v.y);
    Lt[(w4 * 4 + 2) * 260 + c] = f2b(v.z);
    Lt[(w4 * 4 + 3) * 260 + c] = f2b(v.w);
  }
  __syncthreads();

  const int lane = tid & 63, wv = tid >> 6;
  float4 gv = *(const float4*)(gam + lane * 4);
  float4 bv = *(const float4*)(bet + lane * 4);
  const int hdiv = h / 7, hmod = h - hdiv * 7;

  for (int t = 0; t < 14; t++) {
    int w = wv * 14 + t;
    bf16x4_t raw = *(const bf16x4_t*)&Lt[w * 260 + lane * 4];
    float f0 = b2f(raw[0]), f1 = b2f(raw[1]), f2 = b2f(raw[2]), f3 = b2f(raw[3]);
    float sum = f0 + f1 + f2 + f3;
    float sq  = f0*f0 + f1*f1 + f2*f2 + f3*f3;
#pragma unroll
    for (int off = 32; off > 0; off >>= 1) {
      sum += __shfl_xor(sum, off, 64);
      sq  += __shfl_xor(sq,  off, 64);
    }
    float mu = sum * (1.0f / 256.0f);
    float var = sq * (1.0f / 256.0f) - mu * mu;
    float rs = rsqrtf(var + EPS_);
    int wdiv = w / 7, wmod = w - wdiv * 7;
    int tok = b * HW_ + (hdiv * 8 + wdiv) * P_ + hmod * 7 + wmod;
    *(bf16x4_t*)(xtok + (size_t)tok * 256 + lane * 4) = raw;
    bf16x4_t o;
    o[0] = f2b((f0 - mu) * rs * gv.x + bv.x);
    o[1] = f2b((f1 - mu) * rs * gv.y + bv.y);
    o[2] = f2b((f2 - mu) * rs * gv.z + bv.z);
    o[3] = f2b((f3 - mu) * rs * gv.w + bv.w);
    *(bf16x4_t*)(y + (size_t)tok * 256 + lane * 4) = o;
  }
}

// ---------------------------------------------------------------------------
// egress: token-major bf16 -> BCHW f32 out
// ---------------------------------------------------------------------------
__global__ __launch_bounds__(256)
void egress_kernel(const short* __restrict__ outtok, float* __restrict__ out)
{
  const int h = blockIdx.x % 56, b = blockIdx.x / 56;
  const int w = threadIdx.x & 63, cblk = threadIdx.x >> 6;
  const bool act = w < 56;
  const int wcl = act ? w : 55;
  const int tok = b * HW_ + ((h / 7) * 8 + wcl / 7) * P_ + (h % 7) * 7 + (wcl % 7);
  const short* src = outtok + (size_t)tok * 256 + cblk * 64;
  float* dst = out + ((size_t)b * 256 + cblk * 64) * HW_ + h * 56 + w;
#pragma unroll
  for (int j0 = 0; j0 < 64; j0 += 8) {
    bf16x8 r = *(const bf16x8*)(src + j0);
#pragma unroll
    for (int jj = 0; jj < 8; jj++)
      if (act) dst[(size_t)(j0 + jj) * HW_] = b2f(r[jj]);
  }
}

// ---------------------------------------------------------------------------
// attention (MFMA): one wave per (window, head)
// ---------------------------------------------------------------------------
__global__ __launch_bounds__(64)
void attn_kernel(const short* __restrict__ qkv, const short* __restrict__ bt,
                 short* __restrict__ out)
{
  __shared__ short Pbuf[64 * 72];
  const int bid = blockIdx.x;
  const int h = bid & 7;
  const int t0 = (bid >> 3) * P_;
  const int lane = threadIdx.x;
  const int g = lane >> 4, q = lane & 15;

  const short* qb = qkv + (size_t)t0 * 768 + h * 32;

  bf16x8 vf[2][2];
#pragma unroll
  for (int kkt = 0; kkt < 2; kkt++)
#pragma unroll
    for (int n2 = 0; n2 < 2; n2++)
#pragma unroll
      for (int jj = 0; jj < 8; jj++) {
        int key = kkt * 32 + 8 * g + jj; key = key > 48 ? 48 : key;
        vf[kkt][n2][jj] = qb[(size_t)key * 768 + 512 + n2 * 16 + q];
      }

  bf16x8 kf[4], qf[4];
#pragma unroll
  for (int mi = 0; mi < 4; mi++) {
    int r_ = mi * 16 + q; r_ = r_ > 48 ? 48 : r_;
    kf[mi] = *(const bf16x8*)(qb + (size_t)r_ * 768 + 256 + 8 * g);
  }
#pragma unroll
  for (int ni = 0; ni < 4; ni++) {
    int r_ = ni * 16 + q; r_ = r_ > 48 ? 48 : r_;
    qf[ni] = *(const bf16x8*)(qb + (size_t)r_ * 768 + 8 * g);
  }

  f32x4 sacc[4][4] = {};
#pragma unroll
  for (int mi = 0; mi < 4; mi++)
#pragma unroll
    for (int ni = 0; ni < 4; ni++)
      sacc[mi][ni] = __builtin_amdgcn_mfma_f32_16x16x32_bf16(kf[mi], qf[ni], sacc[mi][ni], 0, 0, 0);

  float mx[4] = {-1e30f, -1e30f, -1e30f, -1e30f};
  const short* btb = bt + (size_t)(h * 64) * 64 + q * 4;
#pragma unroll
  for (int mi = 0; mi < 4; mi++)
#pragma unroll
    for (int r = 0; r < 4; r++) {
      int key = mi * 16 + 4 * g + r;
      bf16x4_t bv = *(const bf16x4_t*)(btb + key * 64);
      bool valid = key < P_;
#pragma unroll
      for (int ni = 0; ni < 4; ni++) {
        float s = valid ? fmaf(sacc[mi][ni][r], SCALE_, b2f(bv[ni])) : -1e30f;
        sacc[mi][ni][r] = s;
        mx[ni] = fmaxf(mx[ni], s);
      }
    }
#pragma unroll
  for (int ni = 0; ni < 4; ni++) {
    mx[ni] = fmaxf(mx[ni], __shfl_xor(mx[ni], 16, 64));
    mx[ni] = fmaxf(mx[ni], __shfl_xor(mx[ni], 32, 64));
  }
  float sm[4] = {0.f, 0.f, 0.f, 0.f};
#pragma unroll
  for (int mi = 0; mi < 4; mi++)
#pragma unroll
    for (int ni = 0; ni < 4; ni++)
#pragma unroll
      for (int r = 0; r < 4; r++) {
        float p = __expf(sacc[mi][ni][r] - mx[ni]);
        sacc[mi][ni][r] = p;
        sm[ni] += p;
      }
#pragma unroll
  for (int ni = 0; ni < 4; ni++) {
    sm[ni] += __shfl_xor(sm[ni], 16, 64);
    sm[ni] += __shfl_xor(sm[ni], 32, 64);
    sm[ni] = 1.0f / sm[ni];
  }
#pragma unroll
  for (int ni = 0; ni < 4; ni++)
#pragma unroll
    for (int mi = 0; mi < 4; mi++) {
      bf16x4_t pv;
#pragma unroll
      for (int r = 0; r < 4; r++) pv[r] = f2b(sacc[mi][ni][r] * sm[ni]);
      *(bf16x4_t*)&Pbuf[(ni * 16 + q) * 72 + mi * 16 + 4 * g] = pv;
    }
  __syncthreads();

  f32x4 oacc[4][2] = {};
#pragma unroll
  for (int kkt = 0; kkt < 2; kkt++) {
    bf16x8 paf[4];
#pragma unroll
    for (int qi = 0; qi < 4; qi++)
      paf[qi] = *(const bf16x8*)&Pbuf[(qi * 16 + q) * 72 + kkt * 32 + 8 * g];
#pragma unroll
    for (int qi = 0; qi < 4; qi++)
#pragma unroll
      for (int n2 = 0; n2 < 2; n2++)
        oacc[qi][n2] = __builtin_amdgcn_mfma_f32_16x16x32_bf16(paf[qi], vf[kkt][n2], oacc[qi][n2], 0, 0, 0);
  }

  short* ob = out + (size_t)t0 * 256 + h * 32;
#pragma unroll
  for (int qi = 0; qi < 4; qi++)
#pragma unroll
    for (int r = 0; r < 4; r++) {
      int query = qi * 16 + 4 * g + r;
      if (query < P_) {
#pragma unroll
        for (int n2 = 0; n2 < 2; n2++)
          ob[(size_t)query * 256 + n2 * 16 + q] = f2b(oacc[qi][n2][r]);
      }
    }
}

// ---------------------------------------------------------------------------
// No-LDS register GEMM <EPI, WR, WN, K>: BM=64*WR, BN=64*WN, threads=WR*WN*64.
// A- and B-fragments loaded per-lane DIRECT from global (L2/L1-resident;
// each frag-load = 16 rows x 64B fully-used lines). Zero barriers, zero LDS
// in the K-loop -> compiler pipelines loads across MFMAs; waves free-run.
// XCD remap: all column-siblings of a row-band land on one XCD (L2 reuse).
// EPI 0: bf16 store   EPI 1: gelu(tanh) -> bf16   EPI 2: in-place residual add
// EPI 3 (WR==1, BN==256): residual add + fused LN2 -> res_io + z_out
// ---------------------------------------------------------------------------
template<int EPI, int WR, int WN, int K>
__global__ __launch_bounds__(WR * WN * 64)
void gemm_kernel(const bf16* __restrict__ A, const bf16* __restrict__ Wt,
                 const float* __restrict__ bias, int N,
                 bf16* __restrict__ outb, bf16* __restrict__ res_io,
                 bf16* __restrict__ z_out,
                 const float* __restrict__ gam, const float* __restrict__ bet)
{
  constexpr int BM = WR * 64, BN = WN * 64;
  __shared__ float red1[(EPI == 3) ? 64 : 1][(EPI == 3) ? WN : 1];
  __shared__ float red2[(EPI == 3) ? 64 : 1][(EPI == 3) ? WN : 1];

  const int tid = threadIdx.x;
  const int lane = tid & 63;
  const int wave = tid >> 6;
  const int wr = wave / WN, wc = wave % WN;
  const int l15 = lane & 15, g = lane >> 4;

  // XCD-group remap: column-siblings of one row-band share an XCD
  int bx = blockIdx.x, by = blockIdx.y;
  {
    const int gx = gridDim.x, gy = gridDim.y;
    if (gx > 1) {
      int hwid = blockIdx.x + gx * blockIdx.y;
      int band = gx * 8;
      int fullb = gy >> 3;
      int full = fullb * band;
      if (hwid < full) {
        int g8 = hwid / band, w = hwid % band;
        by = g8 * 8 + (w & 7); bx = w >> 3;
      } else {
        int rem = gy & 7;
        int w = hwid - full;
        by = fullb * 8 + w % rem; bx = w / rem;
      }
    }
  }
  const int bm = by * BM, bn = bx * BN;

  const bf16* Ap[4];
  const bf16* Bp[4];
#pragma unroll
  for (int mi = 0; mi < 4; mi++)
    Ap[mi] = A + (size_t)(bm + wr * 64 + mi * 16 + l15) * K + g * 8;
#pragma unroll
  for (int ni = 0; ni < 4; ni++)
    Bp[ni] = Wt + (size_t)(bn + wc * 64 + ni * 16 + l15) * K + g * 8;

  f32x4 acc[4][4] = {};

  for (int k0 = 0; k0 < K; k0 += 256) {
#pragma unroll
    for (int t = 0; t < 8; ++t) {
      const int k = k0 + t * 32;
      bf16x8 af[4], bfr[4];
#pragma unroll
      for (int mi = 0; mi < 4; mi++) af[mi] = *(const bf16x8*)(Ap[mi] + k);
#pragma unroll
      for (int ni = 0; ni < 4; ni++) bfr[ni] = *(const bf16x8*)(Bp[ni] + k);
#pragma unroll
      for (int mi = 0; mi < 4; mi++)
#pragma unroll
        for (int ni = 0; ni < 4; ni++)
          acc[mi][ni] = __builtin_amdgcn_mfma_f32_16x16x32_bf16(af[mi], bfr[ni], acc[mi][ni], 0, 0, 0);
    }
  }

  if constexpr (EPI == 3) {
    // residual add + fused LayerNorm (WR==1, BN==256==N)
    const int ocol0 = wc * 64;
    float bv[4], gv[4], btv[4];
#pragma unroll
    for (int ni = 0; ni < 4; ni++) {
      bv[ni]  = bias[ocol0 + ni * 16 + l15];
      gv[ni]  = gam[ocol0 + ni * 16 + l15];
      btv[ni] = bet[ocol0 + ni * 16 + l15];
    }
#pragma unroll
    for (int mi = 0; mi < 4; mi++)
#pragma unroll
      for (int r = 0; r < 4; r++) {
        const int rowl = mi * 16 + g * 4 + r;
        float s1 = 0.f, s2 = 0.f;
#pragma unroll
        for (int ni = 0; ni < 4; ni++) {
          const int col = ocol0 + ni * 16 + l15;
          float v = acc[mi][ni][r] + bv[ni]
                  + __bfloat162float(res_io[(size_t)(bm + rowl) * 256 + col]);
          acc[mi][ni][r] = v;
          s1 += v; s2 += v * v;
        }
#pragma unroll
        for (int off = 1; off < 16; off <<= 1) {
          s1 += __shfl_xor(s1, off, 64);
          s2 += __shfl_xor(s2, off, 64);
        }
        if (l15 == 0) { red1[rowl][wc] = s1; red2[rowl][wc] = s2; }
      }
    __syncthreads();
#pragma unroll
    for (int mi = 0; mi < 4; mi++)
#pragma unroll
      for (int r = 0; r < 4; r++) {
        const int rowl = mi * 16 + g * 4 + r;
        float m1 = 0.f, m2 = 0.f;
#pragma unroll
        for (int j = 0; j < WN; j++) { m1 += red1[rowl][j]; m2 += red2[rowl][j]; }
        float mu = m1 * (1.0f / 256.0f);
        float var = m2 * (1.0f / 256.0f) - mu * mu;
        float rs = rsqrtf(var + EPS_);
#pragma unroll
        for (int ni = 0; ni < 4; ni++) {
          const int col = ocol0 + ni * 16 + l15;
          float v = acc[mi][ni][r];
          res_io[(size_t)(bm + rowl) * 256 + col] = __float2bfloat16(v);
          z_out [(size_t)(bm + rowl) * 256 + col] =
              __float2bfloat16((v - mu) * rs * gv[ni] + btv[ni]);
        }
      }
    return;
  }

#pragma unroll
  for (int mi = 0; mi < 4; mi++) {
#pragma unroll
    for (int ni = 0; ni < 4; ni++) {
      const int col = bn + wc * 64 + ni * 16 + l15;
      const float bv = bias[col];
#pragma unroll
      for (int r = 0; r < 4; r++) {
        const int row = bm + wr * 64 + mi * 16 + g * 4 + r;
        float v = acc[mi][ni][r] + bv;
        if (EPI == 0) {
          outb[(size_t)row * N + col] = __float2bfloat16(v);
        } else if (EPI == 1) {
          float u = 0.7978845608f * v * (1.0f + 0.044715f * v * v);
          float e = __expf(2.0f * u);
          float th = 1.0f - 2.0f / (e + 1.0f);
          outb[(size_t)row * N + col] = __float2bfloat16(0.5f * v * (1.0f + th));
        } else {
          size_t o = (size_t)row * 256 + col;
          res_io[o] = __float2bfloat16(v + __bfloat162float(res_io[o]));
        }
      }
    }
  }
}

// ---------------------------------------------------------------------------
extern "C" void kernel_launch(void* const* d_in, const int* in_sizes, int n_in,
                              void* d_out, int out_size, void* d_ws, size_t ws_size,
                              hipStream_t stream)
{
  const float* x      = (const float*)d_in[0];
  const float* ln1_g  = (const float*)d_in[1];
  const float* ln1_b  = (const float*)d_in[2];
  const float* wqkv   = (const float*)d_in[3];
  const float* bqkv   = (const float*)d_in[4];
  const float* wmerge = (const float*)d_in[5];
  const float* bmerge = (const float*)d_in[6];
  const float* btab   = (const float*)d_in[7];
  const float* ln2_g  = (const float*)d_in[8];
  const float* ln2_b  = (const float*)d_in[9];
  const float* w1     = (const float*)d_in[10];
  const float* b1     = (const float*)d_in[11];
  const float* w2     = (const float*)d_in[12];
  const float* b2     = (const float*)d_in[13];
  const int*   relidx = (const int*)d_in[14];
  float* out = (float*)d_out;

  char* ws = (char*)d_ws;
  bf16*  wqkvT   = (bf16*)(ws);                   // 393,216
  bf16*  wmergeT = (bf16*)(ws + 393216);          // 131,072
  bf16*  w1T     = (bf16*)(ws + 524288);          // 524,288
  bf16*  w2T     = (bf16*)(ws + 1048576);         // 524,288
  short* battn   = (short*)(ws + 1572864);        // 65,536
  short* R1      = (short*)(ws + 1638400);        // 25,690,112 residual stream
  short* R2      = (short*)(ws + 27328512);       // 25,690,112 y -> z
  short* qkvc    = (short*)(ws + 53018624);       // 38,535,168 (half-chunk qkv)
  short* attnc   = (short*)(ws + 91553792);       // 12,845,056
  short* hbuf    = (short*)(ws + 53018624);       // 51,380,224 (aliases qkvc+attnc)
  // end: 104,398,848

  prep_kernel<<<3200, 256, 0, stream>>>(wqkv, wmerge, w1, w2, btab, relidx,
                                        wqkvT, wmergeT, w1T, w2T, battn);

  ingest_kernel<<<896, 256, 0, stream>>>(x, ln1_g, ln1_b, R1, R2);

  // attention path, 2 window-aligned chunks of 25088 tokens
  for (int c = 0; c < 2; ++c) {
    size_t r0 = (size_t)c * 25088;
    gemm_kernel<0, 2, 2, 256><<<dim3(6, 196), 256, 0, stream>>>(
        (const bf16*)(R2 + r0 * 256), wqkvT, bqkv, 768, (bf16*)qkvc,
        nullptr, nullptr, nullptr, nullptr);
    attn_kernel<<<4096, 64, 0, stream>>>(qkvc, battn, attnc);
    // merge proj + residual into R1 + fused LN2 -> z (R2)
    gemm_kernel<3, 1, 4, 256><<<dim3(1, 392), 256, 0, stream>>>(
        (const bf16*)attnc, wmergeT, bmerge, 256, nullptr,
        (bf16*)(R1 + r0 * 256), (bf16*)(R2 + r0 * 256), ln2_g, ln2_b);
  }

  // MLP, 2 chunks
  for (int c = 0; c < 2; ++c) {
    size_t r0 = (size_t)c * 25088;
    gemm_kernel<1, 2, 2, 256><<<dim3(8, 196), 256, 0, stream>>>(
        (const bf16*)(R2 + r0 * 256), w1T, b1, 1024, (bf16*)hbuf,
        nullptr, nullptr, nullptr, nullptr);
    gemm_kernel<2, 2, 2, 1024><<<dim3(2, 196), 256, 0, stream>>>(
        (const bf16*)hbuf, w2T, b2, 256, nullptr,
        (bf16*)(R1 + r0 * 256), nullptr, nullptr, nullptr);
  }

  egress_kernel<<<896, 256, 0, stream>>>(R1, out);
}

// Round 10
// 306.783 us; speedup vs baseline: 1.5701x; 1.5701x over previous
//
#include <hip/hip_runtime.h>
#include <hip/hip_bf16.h>

#define B_      16
#define C_      256
#define H_      56
#define W_      56
#define HW_     3136
#define G_      64
#define P_      49
#define NTOK    50176
#define HEADS_  8
#define DH_     32
#define SCALE_  0.0625f
#define EPS_    1e-5f

typedef short bf16x8 __attribute__((ext_vector_type(8)));
typedef short bf16x4_t __attribute__((ext_vector_type(4)));
typedef float f32x4  __attribute__((ext_vector_type(4)));
using bf16 = __hip_bfloat16;

__device__ __forceinline__ void gload16(const void* g, void* l) {
  __builtin_amdgcn_global_load_lds((const __attribute__((address_space(1))) void*)g,
                                   (__attribute__((address_space(3))) void*)l, 16, 0, 0);
}
__device__ __forceinline__ float b2f(short s) {
  union { float f; unsigned u; } v; v.u = ((unsigned)(unsigned short)s) << 16; return v.f;
}
__device__ __forceinline__ short f2b(float f) {   // RNE
  union { float f; unsigned u; } v; v.f = f;
  unsigned r = (v.u + 0x7FFFu + ((v.u >> 16) & 1u)) >> 16;
  return (short)r;
}

// ---------------------------------------------------------------------------
// prep: weights -> [N][K] bf16; bias -> bt[h][key(64)][q*4+qni] bf16
// ---------------------------------------------------------------------------
__global__ __launch_bounds__(256)
void prep_kernel(const float* __restrict__ wqkv, const float* __restrict__ wmerge,
                 const float* __restrict__ w1, const float* __restrict__ w2,
                 const float* __restrict__ btab, const int* __restrict__ relidx,
                 bf16* __restrict__ wqkvT, bf16* __restrict__ wmergeT,
                 bf16* __restrict__ w1T, bf16* __restrict__ w2T,
                 short* __restrict__ bt)
{
  int idx = blockIdx.x * 256 + threadIdx.x;
  if (idx < 196608) { int n = idx >> 8, k = idx & 255;
    wqkvT[idx] = __float2bfloat16(wqkv[k * 768 + n]); return; }
  idx -= 196608;
  if (idx < 65536) { int n = idx >> 8, k = idx & 255;
    wmergeT[idx] = __float2bfloat16(wmerge[k * 256 + n]); return; }
  idx -= 65536;
  if (idx < 262144) { int n = idx >> 8, k = idx & 255;
    w1T[idx] = __float2bfloat16(w1[k * 1024 + n]); return; }
  idx -= 262144;
  if (idx < 262144) { int n = idx >> 10, k = idx & 1023;
    w2T[idx] = __float2bfloat16(w2[k * 256 + n]); return; }
  idx -= 262144;
  if (idx < 32768) {
    int h = idx >> 12, rest = idx & 4095;
    int key = rest >> 6, col = rest & 63;
    int q = col >> 2, qni = col & 3;
    int query = qni * 16 + q;
    float v = 0.f;
    if (key < P_ && query < P_) v = btab[relidx[query * P_ + key] * HEADS_ + h];
    bt[idx] = f2b(v);
  }
}

// ---------------------------------------------------------------------------
// ingest: coalesced BCHW float4 read -> LDS transpose -> LN1 -> xtok + y
// ---------------------------------------------------------------------------
__global__ __launch_bounds__(256)
void ingest_kernel(const float* __restrict__ x, const float* __restrict__ gam,
                   const float* __restrict__ bet, short* __restrict__ xtok,
                   short* __restrict__ y)
{
  __shared__ short Lt[56 * 260];
  const int h = blockIdx.x % 56, b = blockIdx.x / 56;
  const int tid = threadIdx.x;

  const float* xb = x + (size_t)b * 256 * HW_ + h * 56;
#pragma unroll
  for (int i = 0; i < 14; i++) {
    int idx = i * 256 + tid;
    int c = idx / 14, w4 = idx - c * 14;
    float4 v = *(const float4*)(xb + (size_t)c * HW_ + w4 * 4);
    Lt[(w4 * 4 + 0) * 260 + c] = f2b(v.x);
    Lt[(w4 * 4 + 1) * 260 + c] = f2b(v.y);
    Lt[(w4 * 4 + 2) * 260 + c] = f2b(v.z);
    Lt[(w4 * 4 + 3) * 260 + c] = f2b(v.w);
  }
  __syncthreads();

  const int lane = tid & 63, wv = tid >> 6;
  float4 gv = *(const float4*)(gam + lane * 4);
  float4 bv = *(const float4*)(bet + lane * 4);
  const int hdiv = h / 7, hmod = h - hdiv * 7;

  for (int t = 0; t < 14; t++) {
    int w = wv * 14 + t;
    bf16x4_t raw = *(const bf16x4_t*)&Lt[w * 260 + lane * 4];
    float f0 = b2f(raw[0]), f1 = b2f(raw[1]), f2 = b2f(raw[2]), f3 = b2f(raw[3]);
    float sum = f0 + f1 + f2 + f3;
    float sq  = f0*f0 + f1*f1 + f2*f2 + f3*f3;
#pragma unroll
    for (int off = 32; off > 0; off >>= 1) {
      sum += __shfl_xor(sum, off, 64);
      sq  += __shfl_xor(sq,  off, 64);
    }
    float mu = sum * (1.0f / 256.0f);
    float var = sq * (1.0f / 256.0f) - mu * mu;
    float rs = rsqrtf(var + EPS_);
    int wdiv = w / 7, wmod = w - wdiv * 7;
    int tok = b * HW_ + (hdiv * 8 + wdiv) * P_ + hmod * 7 + wmod;
    *(bf16x4_t*)(xtok + (size_t)tok * 256 + lane * 4) = raw;
    bf16x4_t o;
    o[0] = f2b((f0 - mu) * rs * gv.x + bv.x);
    o[1] = f2b((f1 - mu) * rs * gv.y + bv.y);
    o[2] = f2b((f2 - mu) * rs * gv.z + bv.z);
    o[3] = f2b((f3 - mu) * rs * gv.w + bv.w);
    *(bf16x4_t*)(y + (size_t)tok * 256 + lane * 4) = o;
  }
}

// ---------------------------------------------------------------------------
// egress: token-major bf16 -> BCHW f32 out
// ---------------------------------------------------------------------------
__global__ __launch_bounds__(256)
void egress_kernel(const short* __restrict__ outtok, float* __restrict__ out)
{
  const int h = blockIdx.x % 56, b = blockIdx.x / 56;
  const int w = threadIdx.x & 63, cblk = threadIdx.x >> 6;
  const bool act = w < 56;
  const int wcl = act ? w : 55;
  const int tok = b * HW_ + ((h / 7) * 8 + wcl / 7) * P_ + (h % 7) * 7 + (wcl % 7);
  const short* src = outtok + (size_t)tok * 256 + cblk * 64;
  float* dst = out + ((size_t)b * 256 + cblk * 64) * HW_ + h * 56 + w;
#pragma unroll
  for (int j0 = 0; j0 < 64; j0 += 8) {
    bf16x8 r = *(const bf16x8*)(src + j0);
#pragma unroll
    for (int jj = 0; jj < 8; jj++)
      if (act) dst[(size_t)(j0 + jj) * HW_] = b2f(r[jj]);
  }
}

// ---------------------------------------------------------------------------
// attention (MFMA): one wave per (window, head)
// ---------------------------------------------------------------------------
__global__ __launch_bounds__(64)
void attn_kernel(const short* __restrict__ qkv, const short* __restrict__ bt,
                 short* __restrict__ out)
{
  __shared__ short Pbuf[64 * 72];
  const int bid = blockIdx.x;
  const int h = bid & 7;
  const int t0 = (bid >> 3) * P_;
  const int lane = threadIdx.x;
  const int g = lane >> 4, q = lane & 15;

  const short* qb = qkv + (size_t)t0 * 768 + h * 32;

  bf16x8 vf[2][2];
#pragma unroll
  for (int kkt = 0; kkt < 2; kkt++)
#pragma unroll
    for (int n2 = 0; n2 < 2; n2++)
#pragma unroll
      for (int jj = 0; jj < 8; jj++) {
        int key = kkt * 32 + 8 * g + jj; key = key > 48 ? 48 : key;
        vf[kkt][n2][jj] = qb[(size_t)key * 768 + 512 + n2 * 16 + q];
      }

  bf16x8 kf[4], qf[4];
#pragma unroll
  for (int mi = 0; mi < 4; mi++) {
    int r_ = mi * 16 + q; r_ = r_ > 48 ? 48 : r_;
    kf[mi] = *(const bf16x8*)(qb + (size_t)r_ * 768 + 256 + 8 * g);
  }
#pragma unroll
  for (int ni = 0; ni < 4; ni++) {
    int r_ = ni * 16 + q; r_ = r_ > 48 ? 48 : r_;
    qf[ni] = *(const bf16x8*)(qb + (size_t)r_ * 768 + 8 * g);
  }

  f32x4 sacc[4][4] = {};
#pragma unroll
  for (int mi = 0; mi < 4; mi++)
#pragma unroll
    for (int ni = 0; ni < 4; ni++)
      sacc[mi][ni] = __builtin_amdgcn_mfma_f32_16x16x32_bf16(kf[mi], qf[ni], sacc[mi][ni], 0, 0, 0);

  float mx[4] = {-1e30f, -1e30f, -1e30f, -1e30f};
  const short* btb = bt + (size_t)(h * 64) * 64 + q * 4;
#pragma unroll
  for (int mi = 0; mi < 4; mi++)
#pragma unroll
    for (int r = 0; r < 4; r++) {
      int key = mi * 16 + 4 * g + r;
      bf16x4_t bv = *(const bf16x4_t*)(btb + key * 64);
      bool valid = key < P_;
#pragma unroll
      for (int ni = 0; ni < 4; ni++) {
        float s = valid ? fmaf(sacc[mi][ni][r], SCALE_, b2f(bv[ni])) : -1e30f;
        sacc[mi][ni][r] = s;
        mx[ni] = fmaxf(mx[ni], s);
      }
    }
#pragma unroll
  for (int ni = 0; ni < 4; ni++) {
    mx[ni] = fmaxf(mx[ni], __shfl_xor(mx[ni], 16, 64));
    mx[ni] = fmaxf(mx[ni], __shfl_xor(mx[ni], 32, 64));
  }
  float sm[4] = {0.f, 0.f, 0.f, 0.f};
#pragma unroll
  for (int mi = 0; mi < 4; mi++)
#pragma unroll
    for (int ni = 0; ni < 4; ni++)
#pragma unroll
      for (int r = 0; r < 4; r++) {
        float p = __expf(sacc[mi][ni][r] - mx[ni]);
        sacc[mi][ni][r] = p;
        sm[ni] += p;
      }
#pragma unroll
  for (int ni = 0; ni < 4; ni++) {
    sm[ni] += __shfl_xor(sm[ni], 16, 64);
    sm[ni] += __shfl_xor(sm[ni], 32, 64);
    sm[ni] = 1.0f / sm[ni];
  }
#pragma unroll
  for (int ni = 0; ni < 4; ni++)
#pragma unroll
    for (int mi = 0; mi < 4; mi++) {
      bf16x4_t pv;
#pragma unroll
      for (int r = 0; r < 4; r++) pv[r] = f2b(sacc[mi][ni][r] * sm[ni]);
      *(bf16x4_t*)&Pbuf[(ni * 16 + q) * 72 + mi * 16 + 4 * g] = pv;
    }
  __syncthreads();

  f32x4 oacc[4][2] = {};
#pragma unroll
  for (int kkt = 0; kkt < 2; kkt++) {
    bf16x8 paf[4];
#pragma unroll
    for (int qi = 0; qi < 4; qi++)
      paf[qi] = *(const bf16x8*)&Pbuf[(qi * 16 + q) * 72 + kkt * 32 + 8 * g];
#pragma unroll
    for (int qi = 0; qi < 4; qi++)
#pragma unroll
      for (int n2 = 0; n2 < 2; n2++)
        oacc[qi][n2] = __builtin_amdgcn_mfma_f32_16x16x32_bf16(paf[qi], vf[kkt][n2], oacc[qi][n2], 0, 0, 0);
  }

  short* ob = out + (size_t)t0 * 256 + h * 32;
#pragma unroll
  for (int qi = 0; qi < 4; qi++)
#pragma unroll
    for (int r = 0; r < 4; r++) {
      int query = qi * 16 + 4 * g + r;
      if (query < P_) {
#pragma unroll
        for (int n2 = 0; n2 < 2; n2++)
          ob[(size_t)query * 256 + n2 * 16 + q] = f2b(oacc[qi][n2][r]);
      }
    }
}

// ---------------------------------------------------------------------------
// GEMM (R4 structure): BM=128, BN=64*WN, threads=128*WN (WN=2 or 4).
// Double-buffered gload_lds, one barrier per K-step, T2 source swizzle +
// swizzled ds_read.
// EPI 0: bf16 store   EPI 1: gelu(tanh) -> bf16   EPI 2: in-place residual add
// EPI 3 (WN==4): residual add + fused LN2 -> res_io(bf16) + z_out(bf16)
// ---------------------------------------------------------------------------
template<int EPI, int WN>
__global__ __launch_bounds__(128 * WN)
void gemm_kernel(const bf16* __restrict__ A, const bf16* __restrict__ Wt,
                 const float* __restrict__ bias, int N, int K,
                 bf16* __restrict__ outb, short* __restrict__ res_io,
                 short* __restrict__ z_out,
                 const float* __restrict__ gam, const float* __restrict__ bet)
{
  constexpr int THREADS = 128 * WN;
  constexpr int BN = 64 * WN;
  constexpr int RPP = THREADS / 4;      // rows staged per pass
  constexpr int APASS = 128 / RPP;      // 1 (WN=4) or 2 (WN=2)
  __shared__ __align__(16) bf16 As[2][128 * 32];
  __shared__ __align__(16) bf16 Bs[2][BN * 32];
  __shared__ float red1[(EPI == 3) ? 128 : 1][(EPI == 3) ? WN : 1];
  __shared__ float red2[(EPI == 3) ? 128 : 1][(EPI == 3) ? WN : 1];

  const int tid = threadIdx.x;
  const int lane = tid & 63;
  const int wave = tid >> 6;
  const int wr = wave / WN, wc = wave % WN;
  const int bm = blockIdx.y * 128, bn = blockIdx.x * BN;

  f32x4 acc[4][4] = {};

  const int trow = tid >> 2;
  const int tcol = ((tid & 3) ^ ((tid >> 3) & 3)) * 8;   // swizzled source chunk
  const bf16* aA[APASS];
#pragma unroll
  for (int p = 0; p < APASS; p++)
    aA[p] = A + (size_t)(bm + p * RPP + trow) * K + tcol;
  const bf16* aB0 = Wt + (size_t)(bn + trow) * K + tcol;
  const bf16* aB1 = Wt + (size_t)(bn + RPP + trow) * K + tcol;
  const int dOff = tid * 8;

  const int kc_sw = ((lane >> 4) ^ ((lane >> 1) & 3)) * 8;  // swizzled read chunk
  const int l15 = lane & 15, g = lane >> 4;
  const int rA = wr * 64 + l15;
  const int rB = wc * 64 + l15;

  const int nt = K >> 5;

  // prologue: stage tile 0 into buffer 0
#pragma unroll
  for (int p = 0; p < APASS; p++) gload16(aA[p], &As[0][p * RPP * 32 + dOff]);
  gload16(aB0, &Bs[0][dOff]);
  gload16(aB1, &Bs[0][RPP * 32 + dOff]);
  __syncthreads();

  for (int t = 0; t < nt; ++t) {
    const int cur = t & 1;
    if (t + 1 < nt) {
      const int k1 = (t + 1) << 5;
      const int nxt = cur ^ 1;
#pragma unroll
      for (int p = 0; p < APASS; p++) gload16(aA[p] + k1, &As[nxt][p * RPP * 32 + dOff]);
      gload16(aB0 + k1, &Bs[nxt][dOff]);
      gload16(aB1 + k1, &Bs[nxt][RPP * 32 + dOff]);
    }
    bf16x8 af[4], bfr[4];
#pragma unroll
    for (int i = 0; i < 4; i++) {
      af[i]  = *(const bf16x8*)(&As[cur][(rA + i * 16) * 32 + kc_sw]);
      bfr[i] = *(const bf16x8*)(&Bs[cur][(rB + i * 16) * 32 + kc_sw]);
    }
#pragma unroll
    for (int mi = 0; mi < 4; mi++)
#pragma unroll
      for (int ni = 0; ni < 4; ni++)
        acc[mi][ni] = __builtin_amdgcn_mfma_f32_16x16x32_bf16(af[mi], bfr[ni], acc[mi][ni], 0, 0, 0);
    __syncthreads();
  }

  if constexpr (EPI == 3) {
    // residual add + fused LayerNorm over full channel dim (BN == 256 == N)
    const int ocol0 = wc * 64;
    float bv[4], gv[4], btv[4];
#pragma unroll
    for (int ni = 0; ni < 4; ni++) {
      bv[ni]  = bias[ocol0 + ni * 16 + l15];
      gv[ni]  = gam[ocol0 + ni * 16 + l15];
      btv[ni] = bet[ocol0 + ni * 16 + l15];
    }
#pragma unroll
    for (int mi = 0; mi < 4; mi++)
#pragma unroll
      for (int r = 0; r < 4; r++) {
        const int rowl = wr * 64 + mi * 16 + g * 4 + r;
        float s1 = 0.f, s2 = 0.f;
#pragma unroll
        for (int ni = 0; ni < 4; ni++) {
          const int col = ocol0 + ni * 16 + l15;
          float v = acc[mi][ni][r] + bv[ni]
                  + b2f(res_io[(size_t)(bm + rowl) * 256 + col]);
          acc[mi][ni][r] = v;
          s1 += v; s2 += v * v;
        }
#pragma unroll
        for (int off = 1; off < 16; off <<= 1) {  // reduce across the 16 l15-lanes
          s1 += __shfl_xor(s1, off, 64);
          s2 += __shfl_xor(s2, off, 64);
        }
        if (l15 == 0) { red1[rowl][wc] = s1; red2[rowl][wc] = s2; }
      }
    __syncthreads();
#pragma unroll
    for (int mi = 0; mi < 4; mi++)
#pragma unroll
      for (int r = 0; r < 4; r++) {
        const int rowl = wr * 64 + mi * 16 + g * 4 + r;
        float m1 = 0.f, m2 = 0.f;
#pragma unroll
        for (int j = 0; j < WN; j++) { m1 += red1[rowl][j]; m2 += red2[rowl][j]; }
        float mu = m1 * (1.0f / 256.0f);
        float var = m2 * (1.0f / 256.0f) - mu * mu;
        float rs = rsqrtf(var + EPS_);
#pragma unroll
        for (int ni = 0; ni < 4; ni++) {
          const int col = ocol0 + ni * 16 + l15;
          float v = acc[mi][ni][r];
          res_io[(size_t)(bm + rowl) * 256 + col] = f2b(v);
          z_out [(size_t)(bm + rowl) * 256 + col] = f2b((v - mu) * rs * gv[ni] + btv[ni]);
        }
      }
    return;
  }

#pragma unroll
  for (int mi = 0; mi < 4; mi++) {
#pragma unroll
    for (int ni = 0; ni < 4; ni++) {
#pragma unroll
      for (int r = 0; r < 4; r++) {
        const int row = bm + wr * 64 + mi * 16 + g * 4 + r;
        const int col = bn + wc * 64 + ni * 16 + l15;
        float v = acc[mi][ni][r] + bias[col];
        if (EPI == 0) {
          outb[(size_t)row * N + col] = __float2bfloat16(v);
        } else if (EPI == 1) {
          float u = 0.7978845608f * v * (1.0f + 0.044715f * v * v);
          float e = __expf(2.0f * u);
          float th = 1.0f - 2.0f / (e + 1.0f);
          outb[(size_t)row * N + col] = __float2bfloat16(0.5f * v * (1.0f + th));
        } else {
          size_t o = (size_t)row * 256 + col;
          res_io[o] = f2b(v + b2f(res_io[o]));
        }
      }
    }
  }
}

// ---------------------------------------------------------------------------
extern "C" void kernel_launch(void* const* d_in, const int* in_sizes, int n_in,
                              void* d_out, int out_size, void* d_ws, size_t ws_size,
                              hipStream_t stream)
{
  const float* x      = (const float*)d_in[0];
  const float* ln1_g  = (const float*)d_in[1];
  const float* ln1_b  = (const float*)d_in[2];
  const float* wqkv   = (const float*)d_in[3];
  const float* bqkv   = (const float*)d_in[4];
  const float* wmerge = (const float*)d_in[5];
  const float* bmerge = (const float*)d_in[6];
  const float* btab   = (const float*)d_in[7];
  const float* ln2_g  = (const float*)d_in[8];
  const float* ln2_b  = (const float*)d_in[9];
  const float* w1     = (const float*)d_in[10];
  const float* b1     = (const float*)d_in[11];
  const float* w2     = (const float*)d_in[12];
  const float* b2     = (const float*)d_in[13];
  const int*   relidx = (const int*)d_in[14];
  float* out = (float*)d_out;

  char* ws = (char*)d_ws;
  bf16*  wqkvT   = (bf16*)(ws);                   // 393,216
  bf16*  wmergeT = (bf16*)(ws + 393216);          // 131,072
  bf16*  w1T     = (bf16*)(ws + 524288);          // 524,288
  bf16*  w2T     = (bf16*)(ws + 1048576);         // 524,288
  short* battn   = (short*)(ws + 1572864);        // 65,536
  short* R1      = (short*)(ws + 1638400);        // 25,690,112 residual stream
  short* R2      = (short*)(ws + 27328512);       // 25,690,112 y -> z
  short* qkvc    = (short*)(ws + 53018624);       // 38,535,168 (half-chunk qkv)
  short* attnc   = (short*)(ws + 91553792);       // 12,845,056
  short* hbuf    = (short*)(ws + 53018624);       // 51,380,224 (aliases qkvc+attnc)
  // end: 104,398,848

  prep_kernel<<<3200, 256, 0, stream>>>(wqkv, wmerge, w1, w2, btab, relidx,
                                        wqkvT, wmergeT, w1T, w2T, battn);

  ingest_kernel<<<896, 256, 0, stream>>>(x, ln1_g, ln1_b, R1, R2);

  // attention path, 2 window-aligned chunks of 25088 tokens
  for (int c = 0; c < 2; ++c) {
    size_t r0 = (size_t)c * 25088;
    gemm_kernel<0, 4><<<dim3(3, 196), 512, 0, stream>>>(
        (const bf16*)(R2 + r0 * 256), wqkvT, bqkv, 768, 256, (bf16*)qkvc,
        nullptr, nullptr, nullptr, nullptr);
    attn_kernel<<<4096, 64, 0, stream>>>(qkvc, battn, attnc);
    // merge proj + residual into R1 + fused LN2 -> z (R2)
    gemm_kernel<3, 4><<<dim3(1, 196), 512, 0, stream>>>(
        (const bf16*)attnc, wmergeT, bmerge, 256, 256, nullptr,
        R1 + r0 * 256, R2 + r0 * 256, ln2_g, ln2_b);
  }

  // MLP, 2 chunks
  for (int c = 0; c < 2; ++c) {
    size_t r0 = (size_t)c * 25088;
    gemm_kernel<1, 4><<<dim3(4, 196), 512, 0, stream>>>(
        (const bf16*)(R2 + r0 * 256), w1T, b1, 1024, 256, (bf16*)hbuf,
        nullptr, nullptr, nullptr, nullptr);
    gemm_kernel<2, 2><<<dim3(2, 196), 256, 0, stream>>>(
        (const bf16*)hbuf, w2T, b2, 256, 1024, nullptr,
        R1 + r0 * 256, nullptr, nullptr, nullptr);
  }

  egress_kernel<<<896, 256, 0, stream>>>(R1, out);
}